// Round 7
// baseline (1995.402 us; speedup 1.0000x reference)
//
#include <hip/hip_runtime.h>
#include <math.h>

#define SLEN 512

typedef _Float16 half8 __attribute__((ext_vector_type(8)));
typedef _Float16 half2v __attribute__((ext_vector_type(2)));
typedef __fp16 fp16x2 __attribute__((ext_vector_type(2)));
typedef float f32x4 __attribute__((ext_vector_type(4)));
typedef unsigned int uint;

union U4H8 { uint4 u; half8 h; };
union UH2 { uint u; half2v v; fp16x2 p; };

static __device__ __forceinline__ uint packh2(float a, float b){
  UH2 x; x.p = __builtin_amdgcn_cvt_pkrtz(a, b); return x.u;
}
static __device__ __forceinline__ half8 ld_h8(const uint* p){
  U4H8 x; x.u = *(const uint4*)p; return x.h;
}
static __device__ __forceinline__ float rcpf(float x){ return __builtin_amdgcn_rcpf(x); }
static __device__ __forceinline__ float sigm(float v){ return rcpf(1.0f+__expf(-v)); }
static __device__ __forceinline__ float tanh_f(float v){ return 1.0f - 2.0f*rcpf(__expf(2.0f*v)+1.0f); }
static __device__ __forceinline__ float gelu_exact(float v){
  return 0.5f*v*(1.0f+erff(v*0.7071067811865475f));
}
static __device__ __forceinline__ half8 cvt8(const float* p){
  const float4* fp = (const float4*)p;
  float4 v0 = fp[0], v1 = fp[1];
  half8 hv;
  hv[0]=(_Float16)v0.x; hv[1]=(_Float16)v0.y; hv[2]=(_Float16)v0.z; hv[3]=(_Float16)v0.w;
  hv[4]=(_Float16)v1.x; hv[5]=(_Float16)v1.y; hv[6]=(_Float16)v1.z; hv[7]=(_Float16)v1.w;
  return hv;
}
#define MFMA(a,b,c) __builtin_amdgcn_mfma_f32_16x16x32_f16((a),(b),(c),0,0,0)

// ---------------------------------------------------------------------------
// Per-sample precompute: x_enc -> h0[b,128], x_gx[b,384] (+b_ih, +b_hh r/z), yx[b,128] (+yb1)
// ---------------------------------------------------------------------------
__global__ void k_sample(const float* __restrict__ x, const float* __restrict__ xW, const float* __restrict__ xb,
                         const float* __restrict__ h0W, const float* __restrict__ h0b,
                         const float* __restrict__ W_ih, const float* __restrict__ b_ih, const float* __restrict__ b_hh,
                         const float* __restrict__ yW1, const float* __restrict__ yb1,
                         float* __restrict__ w_h0, float* __restrict__ w_xgx, float* __restrict__ w_yx)
{
  const int b = blockIdx.x, tid = threadIdx.x;   // 384 threads
  __shared__ float sx[128];
  __shared__ float sxe[128];
  if (tid < 128) sx[tid] = x[b*128+tid];
  __syncthreads();
  if (tid < 128) {
    float acc = xb[tid];
    #pragma unroll 8
    for (int j=0;j<128;++j) acc += xW[tid*128+j]*sx[j];
    sxe[tid] = acc;
  }
  __syncthreads();
  {
    const int o = tid;
    float acc = b_ih[o] + (o < 256 ? b_hh[o] : 0.f);   // fold b_hh for r,z only
    #pragma unroll 8
    for (int j=0;j<128;++j) acc += W_ih[o*177+j]*sxe[j];
    w_xgx[b*384+o] = acc;
  }
  if (tid < 128) {
    float acc = h0b[tid];
    #pragma unroll 8
    for (int j=0;j<128;++j) acc += h0W[tid*128+j]*sxe[j];
    w_h0[b*128+tid] = tanhf(acc);
    float a2 = yb1[tid];
    #pragma unroll 8
    for (int j=0;j<128;++j) a2 += yW1[tid*304+128+j]*sxe[j];
    w_yx[b*128+tid] = a2;
  }
}

// ---------------------------------------------------------------------------
// FUSED recurrence + heads. 64 WGs x 512 thr (8 waves), 16 samples/WG.
// Wave wv owns rows [wv*16, wv*16+16) of r,z,n (GRU) AND unit-tile wv of the
// t-head and y-head layer-1 (the B-operand is the SAME hb fragment). GRU
// combine is register-local. gelu outputs go to a parity-double-buffered LDS
// buffer; waves 6/7 run layer-2 one step behind and store o_t/o_y. Each wave
// stores its 16 channels of o_h (f32) straight from hb. No h16, no k_heads.
// LDS anti-conflict: s_h/s_g slots XOR-swizzled by (c&7); s_chunk transposed
// to [arr][st][sample]; s_al stride 20.
// ---------------------------------------------------------------------------
__global__ __launch_bounds__(512,1) void k_recur_fused(
  const float* __restrict__ W_hh, const float* __restrict__ W_ih, const float* __restrict__ b_hh,
  const int* __restrict__ a, const int* __restrict__ tt,
  const float* __restrict__ yy, const float* __restrict__ mask,
  const float* __restrict__ w_h0, const float* __restrict__ w_xgx, const float* __restrict__ w_yx,
  const float* __restrict__ a_emb, const float* __restrict__ t_emb,
  const float* __restrict__ tW1, const float* __restrict__ tb1,
  const float* __restrict__ tW2, const float* __restrict__ tb2,
  const float* __restrict__ yW1, const float* __restrict__ yW2, const float* __restrict__ yb2,
  float* __restrict__ o_y, float* __restrict__ o_t, float* __restrict__ o_h)
{
  const int tid = threadIdx.x;
  const int wv = tid>>6, lane = tid&63, q = lane>>4, c = lane&15;
  const int b0 = blockIdx.x*16;
  const int r0 = wv*16;
  const int swz = c&7;

  __shared__ __align__(16) uint s_h[2][16*64];       // h f16, slot-swizzled
  __shared__ __align__(16) uint s_g[2][2][16*64];    // gelu f16 [head][par], swizzled
  __shared__ __align__(16) uint s_chunk[2][1024];    // [par][arr*256 + st*16 + c]
  __shared__ __align__(16) uint s_al[100*20];        // a_emb packed f16, stride 20
  __shared__ __align__(16) uint s_te[32];            // t_emb packed f16 [4][8]

  // ---- GRU stationary A-frags: wf[g*6+kt]
  half8 wf[18];
  #pragma unroll
  for (int g=0; g<3; ++g) {
    const int row = g*128 + r0 + c;
    #pragma unroll
    for (int kt=0; kt<4; ++kt) wf[g*6+kt] = cvt8(W_hh + row*128 + kt*32 + q*8);
    #pragma unroll
    for (int kt=4; kt<6; ++kt) {
      half8 hv;
      #pragma unroll
      for (int j=0;j<8;++j) {
        int k2 = (kt-4)*32 + q*8 + j;
        float v = (k2 < 49) ? W_ih[row*177 + 128 + k2] : 0.f;
        hv[j] = (_Float16)v;
      }
      wf[g*6+kt] = hv;
    }
  }
  // ---- head layer-1 A-frags: wave wv owns unit-tile wv of each head
  half8 wt[4], wy[6];
  {
    const int urow = r0 + c;
    #pragma unroll
    for (int kt=0; kt<4; ++kt) {
      wt[kt] = cvt8(tW1 + urow*128 + kt*32 + q*8);
      wy[kt] = cvt8(yW1 + urow*304 + kt*32 + q*8);
    }
    wy[4] = cvt8(yW1 + urow*304 + 256 + q*8);      // ae block (32 cols, all valid)
    half8 hv;
    #pragma unroll
    for (int j=0;j<8;++j) {
      int k2 = 32 + q*8 + j;                        // te block (48 total, zero-pad)
      hv[j] = (_Float16)((k2 < 48) ? yW1[urow*304 + 256 + k2] : 0.f);
    }
    wy[5] = hv;
  }
  // ---- layer-2 A-frags (waves 6,7)
  half8 w2f[4];
  if (wv == 6) {
    #pragma unroll
    for (int kt=0;kt<4;++kt) {
      half8 hv;
      #pragma unroll
      for (int j=0;j<8;++j) hv[j] = (_Float16)((c < 4) ? tW2[c*128 + kt*32 + q*8 + j] : 0.f);
      w2f[kt] = hv;
    }
  } else if (wv == 7) {
    #pragma unroll
    for (int kt=0;kt<4;++kt) {
      half8 hv;
      #pragma unroll
      for (int j=0;j<8;++j) hv[j] = (_Float16)((c == 0) ? yW2[kt*32 + q*8 + j] : 0.f);
      w2f[kt] = hv;
    }
  }
  f32x4 tb2r; float yb2s = yb2[0];
  #pragma unroll
  for (int r=0;r<4;++r) tb2r[r] = tb2[r];
  // ---- per-lane state + head pre-adds
  f32x4 xgr, xgz, xgn, bhh, hm, tb1r, wyx0;
  #pragma unroll
  for (int j=0;j<4;++j) {
    const int rr = r0 + q*4 + j;
    xgr[j] = w_xgx[(b0+c)*384 +       rr];
    xgz[j] = w_xgx[(b0+c)*384 + 128 + rr];
    xgn[j] = w_xgx[(b0+c)*384 + 256 + rr];
    bhh[j] = b_hh[256 + rr];
    hm[j]  = w_h0[(b0+c)*128 + rr];
    tb1r[j] = tb1[rr];
    wyx0[j] = w_yx[(b0+c)*128 + rr];
  }
  // ---- stage embedding tables
  for (int d = tid; d < 1600; d += 512) {
    int row = d>>4, col = d&15;
    s_al[row*20+col] = packh2(a_emb[row*32+2*col], a_emb[row*32+2*col+1]);
  }
  if (tid < 32) {
    int row = tid>>3, col = tid&7;
    s_te[tid] = packh2(t_emb[row*16+2*col], t_emb[row*16+2*col+1]);
  }
  // ---- chunk 0 (wave 0), transposed [arr][st][c]
  uint4 cr0, cr1, cr2, cr3;
  if (wv==0) {
    const uint* bp = (q==0) ? (const uint*)a : (q==1) ? (const uint*)tt
                   : (q==2) ? (const uint*)yy : (const uint*)mask;
    const uint4* p = (const uint4*)(bp + (size_t)(b0+c)*512);
    cr0=p[0]; cr1=p[1]; cr2=p[2]; cr3=p[3];
    uint* dst = &s_chunk[0][q*256 + c];
    dst[0*16]=cr0.x;  dst[1*16]=cr0.y;  dst[2*16]=cr0.z;  dst[3*16]=cr0.w;
    dst[4*16]=cr1.x;  dst[5*16]=cr1.y;  dst[6*16]=cr1.z;  dst[7*16]=cr1.w;
    dst[8*16]=cr2.x;  dst[9*16]=cr2.y;  dst[10*16]=cr2.z; dst[11*16]=cr2.w;
    dst[12*16]=cr3.x; dst[13*16]=cr3.y; dst[14*16]=cr3.z; dst[15*16]=cr3.w;
  }
  // ---- h0 -> s_h[0] (swizzled slots)
  {
    const int slot = wv*2 + (q>>1);
    const int hidx = c*64 + ((slot ^ swz)<<2) + (q&1)*2;
    uint2 u; u.x = packh2(hm[0], hm[1]); u.y = packh2(hm[2], hm[3]);
    *(uint2*)&s_h[0][hidx] = u;
  }
  __syncthreads();

  for (int s=0; s<SLEN; ++s) {
    const int pb = s&1, par = (s>>4)&1, st = s&15;
    // ---- h B-frags (swizzled)
    half8 hb[4];
    #pragma unroll
    for (int kt=0;kt<4;++kt) hb[kt] = ld_h8(&s_h[pb][c*64 + (((kt*4+q)^swz)<<2)]);
    // ---- chunk scalars (transposed: conflict-free, q-broadcast)
    const int av = (int)s_chunk[par][        st*16 + c];
    const int tv = (int)s_chunk[par][256   + st*16 + c];
    const float yv   = __uint_as_float(s_chunk[par][512 + st*16 + c]);
    const float mval = __uint_as_float(s_chunk[par][768 + st*16 + c]);
    half8 eb0 = ld_h8(&s_al[av*20 + q*4]);
    half8 eb1;
    if (q < 2) eb1 = ld_h8(&s_te[tv*8 + q*4]);
    else { U4H8 t; t.u = make_uint4((q==2)?packh2(yv,0.f):0u,0u,0u,0u); eb1 = t.h; }

    // ---- layer-2 for step s-1 (waves 6/7), reads s_g[(s-1)&1] (barrier-safe)
    if (wv >= 6 && s > 0) {
      const int hd = wv & 1, pp = (s-1)&1;
      f32x4 a2; a2[0]=0.f; a2[1]=0.f; a2[2]=0.f; a2[3]=0.f;
      #pragma unroll
      for (int kt=0;kt<4;++kt) {
        half8 gb = ld_h8(&s_g[hd][pp][c*64 + (((kt*4+q)^swz)<<2)]);
        a2 = MFMA(w2f[kt], gb, a2);
      }
      if (lane < 16) {
        const size_t p = (size_t)(b0+c)*SLEN + (s-1);
        if (hd == 0) {
          *(float4*)&o_t[p*4] = make_float4(a2[0]+tb2r[0], a2[1]+tb2r[1], a2[2]+tb2r[2], a2[3]+tb2r[3]);
        } else {
          o_y[p] = a2[0] + yb2s;
        }
      }
    }
    // ---- o_h store straight from hb (wave wv stores its 16 channels)
    if ((q>>1) == (wv&1)) {
      const int kt = wv>>1;
      float* op = o_h + ((size_t)(b0+c)*SLEN + s)*128 + kt*32 + q*8;
      *(float4*)op     = make_float4((float)hb[kt][0], (float)hb[kt][1], (float)hb[kt][2], (float)hb[kt][3]);
      *(float4*)(op+4) = make_float4((float)hb[kt][4], (float)hb[kt][5], (float)hb[kt][6], (float)hb[kt][7]);
    }

    // ---- 28 MFMA: GRU r(6), z(6), n_h(4), n_x(2) + heads t(4), y(6)
    f32x4 ar = xgr, az = xgz, anh = bhh, anx = xgn, at = tb1r, ay = wyx0;
    #pragma unroll
    for (int kt=0;kt<4;++kt) {
      ar  = MFMA(wf[kt],    hb[kt], ar);
      az  = MFMA(wf[6+kt],  hb[kt], az);
      anh = MFMA(wf[12+kt], hb[kt], anh);
      at  = MFMA(wt[kt],    hb[kt], at);
      ay  = MFMA(wy[kt],    hb[kt], ay);
    }
    ar  = MFMA(wf[4],  eb0, ar);   ar  = MFMA(wf[5],  eb1, ar);
    az  = MFMA(wf[10], eb0, az);   az  = MFMA(wf[11], eb1, az);
    anx = MFMA(wf[16], eb0, anx);  anx = MFMA(wf[17], eb1, anx);
    ay  = MFMA(wy[4],  eb0, ay);   ay  = MFMA(wy[5],  eb1, ay);   // y-weights 0 where eb1 holds y

    // ---- register-local GRU combine
    #pragma unroll
    for (int j=0;j<4;++j) {
      float rj = sigm(ar[j]), zj = sigm(az[j]);
      float nj = tanh_f(anx[j] + rj*anh[j]);
      float hn = nj + zj*(hm[j] - nj);
      hm[j] = hm[j] + mval*(hn - hm[j]);
    }
    // ---- write h(s+1) (swizzled)
    {
      const int slot = wv*2 + (q>>1);
      const int hidx = c*64 + ((slot ^ swz)<<2) + (q&1)*2;
      uint2 u; u.x = packh2(hm[0], hm[1]); u.y = packh2(hm[2], hm[3]);
      *(uint2*)&s_h[(s+1)&1][hidx] = u;
    }
    // ---- gelu + stage for layer-2 (parity s&1)
    {
      const int slot = wv*2 + (q>>1);
      const int gidx = c*64 + ((slot ^ swz)<<2) + (q&1)*2;
      uint2 ut, uy;
      ut.x = packh2(gelu_exact(at[0]), gelu_exact(at[1]));
      ut.y = packh2(gelu_exact(at[2]), gelu_exact(at[3]));
      uy.x = packh2(gelu_exact(ay[0]), gelu_exact(ay[1]));
      uy.y = packh2(gelu_exact(ay[2]), gelu_exact(ay[3]));
      *(uint2*)&s_g[0][s&1][gidx] = ut;
      *(uint2*)&s_g[1][s&1][gidx] = uy;
    }
    // ---- chunk prefetch (wave 0)
    if (wv==0) {
      if (st==8 && s<490) {
        const int s0n = ((s>>4)+1)*16;
        const uint* bp = (q==0) ? (const uint*)a : (q==1) ? (const uint*)tt
                       : (q==2) ? (const uint*)yy : (const uint*)mask;
        const uint4* p = (const uint4*)(bp + (size_t)(b0+c)*512 + s0n);
        cr0=p[0]; cr1=p[1]; cr2=p[2]; cr3=p[3];
      }
      if (st==9 && s<491) {
        uint* dst = &s_chunk[((s>>4)+1)&1][q*256 + c];
        dst[0*16]=cr0.x;  dst[1*16]=cr0.y;  dst[2*16]=cr0.z;  dst[3*16]=cr0.w;
        dst[4*16]=cr1.x;  dst[5*16]=cr1.y;  dst[6*16]=cr1.z;  dst[7*16]=cr1.w;
        dst[8*16]=cr2.x;  dst[9*16]=cr2.y;  dst[10*16]=cr2.z; dst[11*16]=cr2.w;
        dst[12*16]=cr3.x; dst[13*16]=cr3.y; dst[14*16]=cr3.z; dst[15*16]=cr3.w;
      }
    }
    __syncthreads();   // ONE barrier per step (full fence: safe for new code)
  }
  // ---- tail: layer-2 for s = 511 (parity 1)
  if (wv >= 6) {
    const int hd = wv & 1;
    f32x4 a2; a2[0]=0.f; a2[1]=0.f; a2[2]=0.f; a2[3]=0.f;
    #pragma unroll
    for (int kt=0;kt<4;++kt) {
      half8 gb = ld_h8(&s_g[hd][1][c*64 + (((kt*4+q)^swz)<<2)]);
      a2 = MFMA(w2f[kt], gb, a2);
    }
    if (lane < 16) {
      const size_t p = (size_t)(b0+c)*SLEN + (SLEN-1);
      if (hd == 0) {
        *(float4*)&o_t[p*4] = make_float4(a2[0]+tb2r[0], a2[1]+tb2r[1], a2[2]+tb2r[2], a2[3]+tb2r[3]);
      } else {
        o_y[p] = a2[0] + yb2s;
      }
    }
  }
}

// ---------------------------------------------------------------------------
extern "C" void kernel_launch(void* const* d_in, const int* in_sizes, int n_in,
                              void* d_out, int out_size, void* d_ws, size_t ws_size,
                              hipStream_t stream) {
  (void)in_sizes; (void)n_in; (void)out_size; (void)ws_size;
  const float* x     = (const float*)d_in[0];
  const int*   a     = (const int*)  d_in[1];
  const int*   tt    = (const int*)  d_in[2];
  const float* y     = (const float*)d_in[3];
  const float* mask  = (const float*)d_in[4];
  const float* xW    = (const float*)d_in[5];
  const float* xb    = (const float*)d_in[6];
  const float* a_emb = (const float*)d_in[7];
  const float* t_emb = (const float*)d_in[8];
  const float* W_ih  = (const float*)d_in[9];
  const float* b_ih  = (const float*)d_in[10];
  const float* W_hh  = (const float*)d_in[11];
  const float* b_hh  = (const float*)d_in[12];
  const float* h0W   = (const float*)d_in[13];
  const float* h0b   = (const float*)d_in[14];
  const float* tW1   = (const float*)d_in[15];
  const float* tb1   = (const float*)d_in[16];
  const float* tW2   = (const float*)d_in[17];
  const float* tb2   = (const float*)d_in[18];
  const float* yW1   = (const float*)d_in[19];
  const float* yb1   = (const float*)d_in[20];
  const float* yW2   = (const float*)d_in[21];
  const float* yb2   = (const float*)d_in[22];

  float* o_y = (float*)d_out;                  // [B,S,1]   524288
  float* o_t = o_y + 524288;                   // [B,S,4]   2097152
  float* o_h = o_y + 2621440;                  // [B,S,128] 67108864

  float* ws    = (float*)d_ws;
  float* w_h0  = ws;                 // 131072
  float* w_xgx = ws + 131072;        // 393216
  float* w_yx  = ws + 524288;        // 131072

  k_sample<<<1024, 384, 0, stream>>>(x, xW, xb, h0W, h0b, W_ih, b_ih, b_hh, yW1, yb1,
                                     w_h0, w_xgx, w_yx);
  k_recur_fused<<<64, 512, 0, stream>>>(W_hh, W_ih, b_hh, a, tt, y, mask,
                                        w_h0, w_xgx, w_yx, a_emb, t_emb,
                                        tW1, tb1, tW2, tb2, yW1, yW2, yb2,
                                        o_y, o_t, o_h);
}

// Round 8
// 1108.575 us; speedup vs baseline: 1.8000x; 1.8000x over previous
//
#include <hip/hip_runtime.h>
#include <math.h>

#define SLEN 512

typedef _Float16 half8 __attribute__((ext_vector_type(8)));
typedef _Float16 half2v __attribute__((ext_vector_type(2)));
typedef __fp16 fp16x2 __attribute__((ext_vector_type(2)));
typedef float f32x4 __attribute__((ext_vector_type(4)));
typedef unsigned int uint;

union U4H8 { uint4 u; half8 h; };
union UH2 { uint u; half2v v; fp16x2 p; };

static __device__ __forceinline__ uint packh2(float a, float b){
  UH2 x; x.p = __builtin_amdgcn_cvt_pkrtz(a, b); return x.u;
}
static __device__ __forceinline__ half8 ld_h8(const uint* p){
  U4H8 x; x.u = *(const uint4*)p; return x.h;
}
static __device__ __forceinline__ float rcpf(float x){ return __builtin_amdgcn_rcpf(x); }
static __device__ __forceinline__ float sigm(float v){ return rcpf(1.0f+__expf(-v)); }
static __device__ __forceinline__ float tanh_f(float v){ return 1.0f - 2.0f*rcpf(__expf(2.0f*v)+1.0f); }
static __device__ __forceinline__ float gelu_exact(float v){
  return 0.5f*v*(1.0f+erff(v*0.7071067811865475f));
}
static __device__ __forceinline__ half8 cvt8(const float* p){
  const float4* fp = (const float4*)p;
  float4 v0 = fp[0], v1 = fp[1];
  half8 hv;
  hv[0]=(_Float16)v0.x; hv[1]=(_Float16)v0.y; hv[2]=(_Float16)v0.z; hv[3]=(_Float16)v0.w;
  hv[4]=(_Float16)v1.x; hv[5]=(_Float16)v1.y; hv[6]=(_Float16)v1.z; hv[7]=(_Float16)v1.w;
  return hv;
}
#define MFMA(a,b,c) __builtin_amdgcn_mfma_f32_16x16x32_f16((a),(b),(c),0,0,0)

// LDS-visibility-only workgroup barrier (no vmcnt drain).
static __device__ __forceinline__ void wg_sync(){
  asm volatile("s_waitcnt lgkmcnt(0)" ::: "memory");
  __builtin_amdgcn_s_barrier();
}

// ---------------------------------------------------------------------------
// Per-sample precompute: x_enc -> h0[b,128], x_gx[b,384] (+b_ih, +b_hh r/z), yx[b,128] (+yb1)
// xW/h0W/yW1 rows are 16B-aligned -> float4 loads; W_ih rows (708B) stay scalar.
// ---------------------------------------------------------------------------
__global__ void k_sample(const float* __restrict__ x, const float* __restrict__ xW, const float* __restrict__ xb,
                         const float* __restrict__ h0W, const float* __restrict__ h0b,
                         const float* __restrict__ W_ih, const float* __restrict__ b_ih, const float* __restrict__ b_hh,
                         const float* __restrict__ yW1, const float* __restrict__ yb1,
                         float* __restrict__ w_h0, float* __restrict__ w_xgx, float* __restrict__ w_yx)
{
  const int b = blockIdx.x, tid = threadIdx.x;   // 384 threads
  __shared__ float sx[128];
  __shared__ float sxe[128];
  if (tid < 128) sx[tid] = x[b*128+tid];
  __syncthreads();
  if (tid < 128) {
    float acc = xb[tid];
    const float4* wr = (const float4*)(xW + tid*128);
    #pragma unroll 8
    for (int j=0;j<32;++j) {
      float4 w = wr[j];
      acc += w.x*sx[4*j] + w.y*sx[4*j+1] + w.z*sx[4*j+2] + w.w*sx[4*j+3];
    }
    sxe[tid] = acc;
  }
  __syncthreads();
  {
    const int o = tid;
    float acc = b_ih[o] + (o < 256 ? b_hh[o] : 0.f);   // fold b_hh for r,z only
    #pragma unroll 8
    for (int j=0;j<128;++j) acc += W_ih[o*177+j]*sxe[j];
    w_xgx[b*384+o] = acc;
  }
  if (tid < 128) {
    float acc = h0b[tid];
    const float4* hr = (const float4*)(h0W + tid*128);
    #pragma unroll 8
    for (int j=0;j<32;++j) {
      float4 w = hr[j];
      acc += w.x*sxe[4*j] + w.y*sxe[4*j+1] + w.z*sxe[4*j+2] + w.w*sxe[4*j+3];
    }
    w_h0[b*128+tid] = tanhf(acc);
    float a2 = yb1[tid];
    const float4* yr = (const float4*)(yW1 + tid*304 + 128);
    #pragma unroll 8
    for (int j=0;j<32;++j) {
      float4 w = yr[j];
      a2 += w.x*sxe[4*j] + w.y*sxe[4*j+1] + w.z*sxe[4*j+2] + w.w*sxe[4*j+3];
    }
    w_yx[b*128+tid] = a2;
  }
}

// ---------------------------------------------------------------------------
// MFMA recurrence, ONE lgkm-only barrier per step. 64 WGs x 512 thr (8 waves),
// 16 samples per WG. Wave wv owns h-rows [wv*16, wv*16+16) of r,z,n; GRU
// combine is register-local; h(s) stored straight from registers to h16 (f16)
// or o_h (f32 fallback). LDS anti-conflict (ported from the correctness-
// verified r7 kernel): s_h slots XOR-swizzled by (c&7); s_chunk transposed
// to [arr][st][sample]; s_al stride 20.
// ---------------------------------------------------------------------------
__global__ __launch_bounds__(512,1) void k_recur(
  const float* __restrict__ W_hh, const float* __restrict__ W_ih, const float* __restrict__ b_hh,
  const int* __restrict__ a, const int* __restrict__ tt,
  const float* __restrict__ yy, const float* __restrict__ mask,
  const float* __restrict__ w_h0, const float* __restrict__ w_xgx,
  const float* __restrict__ a_emb, const float* __restrict__ t_emb,
  float* __restrict__ o_h, uint* __restrict__ h16)
{
  const int tid = threadIdx.x;
  const int wv = tid>>6, lane = tid&63, q = lane>>4, c = lane&15;
  const int b0 = blockIdx.x*16;
  const int r0 = wv*16;
  const int swz = c&7;

  __shared__ __align__(16) uint s_h[2][16*64];     // h f16, slot-swizzled
  __shared__ __align__(16) uint s_chunk[2][1024];  // [par][arr*256 + st*16 + c]
  __shared__ __align__(16) uint s_al[100*20];      // a_emb packed f16, stride 20
  __shared__ __align__(16) uint s_te[32];          // t_emb packed f16 [4][8]

  // ---- stationary weight A-frags: wf[g*6+kt], g=0(r),1(z),2(n)
  half8 wf[18];
  #pragma unroll
  for (int g=0; g<3; ++g) {
    const int row = g*128 + r0 + c;
    #pragma unroll
    for (int kt=0; kt<4; ++kt) wf[g*6+kt] = cvt8(W_hh + row*128 + kt*32 + q*8);
    #pragma unroll
    for (int kt=4; kt<6; ++kt) {
      half8 hv;
      #pragma unroll
      for (int j=0;j<8;++j) {
        int k2 = (kt-4)*32 + q*8 + j;
        float v = (k2 < 49) ? W_ih[row*177 + 128 + k2] : 0.f;
        hv[j] = (_Float16)v;
      }
      wf[g*6+kt] = hv;
    }
  }
  // per-lane state: 4 rows (r0 + q*4 + j) x sample c
  f32x4 xgr, xgz, xgn, bhh, hm;
  #pragma unroll
  for (int j=0;j<4;++j) {
    const int rr = r0 + q*4 + j;
    xgr[j] = w_xgx[(b0+c)*384 +       rr];
    xgz[j] = w_xgx[(b0+c)*384 + 128 + rr];
    xgn[j] = w_xgx[(b0+c)*384 + 256 + rr];
    bhh[j] = b_hh[256 + rr];
    hm[j]  = w_h0[(b0+c)*128 + rr];
  }
  // stage embedding tables (packed f16, stride 20)
  for (int d = tid; d < 1600; d += 512) {
    int row = d>>4, col = d&15;
    s_al[row*20+col] = packh2(a_emb[row*32+2*col], a_emb[row*32+2*col+1]);
  }
  if (tid < 32) {
    int row = tid>>3, col = tid&7;
    s_te[tid] = packh2(t_emb[row*16+2*col], t_emb[row*16+2*col+1]);
  }
  // chunk 0 (wave 0), transposed [arr][st][c]
  uint4 cr0, cr1, cr2, cr3;
  if (wv==0) {
    const uint* bp = (q==0) ? (const uint*)a : (q==1) ? (const uint*)tt
                   : (q==2) ? (const uint*)yy : (const uint*)mask;
    const uint4* p = (const uint4*)(bp + (size_t)(b0+c)*512);
    cr0=p[0]; cr1=p[1]; cr2=p[2]; cr3=p[3];
    uint* dst = &s_chunk[0][q*256 + c];
    dst[0*16]=cr0.x;  dst[1*16]=cr0.y;  dst[2*16]=cr0.z;  dst[3*16]=cr0.w;
    dst[4*16]=cr1.x;  dst[5*16]=cr1.y;  dst[6*16]=cr1.z;  dst[7*16]=cr1.w;
    dst[8*16]=cr2.x;  dst[9*16]=cr2.y;  dst[10*16]=cr2.z; dst[11*16]=cr2.w;
    dst[12*16]=cr3.x; dst[13*16]=cr3.y; dst[14*16]=cr3.z; dst[15*16]=cr3.w;
  }
  // h0 -> s_h[0] (swizzled slots)
  {
    const int slot = wv*2 + (q>>1);
    const int hidx = c*64 + ((slot ^ swz)<<2) + (q&1)*2;
    uint2 u; u.x = packh2(hm[0], hm[1]); u.y = packh2(hm[2], hm[3]);
    *(uint2*)&s_h[0][hidx] = u;
  }
  __syncthreads();

  for (int s=0; s<SLEN; ++s) {
    const int pb = s&1, par = (s>>4)&1, st = s&15;
    // ---- h B-frags (swizzled)
    half8 hb[4];
    #pragma unroll
    for (int kt=0;kt<4;++kt) hb[kt] = ld_h8(&s_h[pb][c*64 + (((kt*4+q)^swz)<<2)]);
    // ---- chunk scalars (transposed: conflict-free, q-broadcast)
    const int av = (int)s_chunk[par][        st*16 + c];
    const int tv = (int)s_chunk[par][256   + st*16 + c];
    const float yv   = __uint_as_float(s_chunk[par][512 + st*16 + c]);
    const float mval = __uint_as_float(s_chunk[par][768 + st*16 + c]);
    half8 eb0 = ld_h8(&s_al[av*20 + q*4]);
    half8 eb1;
    if (q < 2) eb1 = ld_h8(&s_te[tv*8 + q*4]);
    else { U4H8 t; t.u = make_uint4((q==2)?packh2(yv,0.f):0u,0u,0u,0u); eb1 = t.h; }
    // ---- store h(s) (pre-update state) straight from registers
    {
      const size_t p = (size_t)(b0+c)*SLEN + s;
      if (h16) {
        uint2 u; u.x = packh2(hm[0], hm[1]); u.y = packh2(hm[2], hm[3]);
        *(uint2*)(h16 + p*64 + wv*8 + q*2) = u;
      } else {
        *(float4*)(o_h + p*128 + r0 + q*4) = make_float4(hm[0],hm[1],hm[2],hm[3]);
      }
    }
    // ---- 18 MFMA: r(6), z(6), n_h(4), n_x(2)
    f32x4 ar = xgr, az = xgz, anh = bhh, anx = xgn;
    #pragma unroll
    for (int kt=0;kt<4;++kt) {
      ar  = MFMA(wf[kt],      hb[kt], ar);
      az  = MFMA(wf[6+kt],    hb[kt], az);
      anh = MFMA(wf[12+kt],   hb[kt], anh);
    }
    ar  = MFMA(wf[4],  eb0, ar);   ar  = MFMA(wf[5],  eb1, ar);
    az  = MFMA(wf[10], eb0, az);   az  = MFMA(wf[11], eb1, az);
    anx = MFMA(wf[16], eb0, anx);  anx = MFMA(wf[17], eb1, anx);
    // ---- register-local GRU combine
    #pragma unroll
    for (int j=0;j<4;++j) {
      float rj = sigm(ar[j]), zj = sigm(az[j]);
      float nj = tanh_f(anx[j] + rj*anh[j]);
      float hn = nj + zj*(hm[j] - nj);
      hm[j] = hm[j] + mval*(hn - hm[j]);
    }
    // ---- write h(s+1) (swizzled)
    {
      const int slot = wv*2 + (q>>1);
      const int hidx = c*64 + ((slot ^ swz)<<2) + (q&1)*2;
      uint2 u; u.x = packh2(hm[0], hm[1]); u.y = packh2(hm[2], hm[3]);
      *(uint2*)&s_h[(s+1)&1][hidx] = u;
    }
    // ---- chunk prefetch (wave 0), transposed store
    if (wv==0) {
      if (st==8 && s<490) {
        const int s0n = ((s>>4)+1)*16;
        const uint* bp = (q==0) ? (const uint*)a : (q==1) ? (const uint*)tt
                       : (q==2) ? (const uint*)yy : (const uint*)mask;
        const uint4* p = (const uint4*)(bp + (size_t)(b0+c)*512 + s0n);
        cr0=p[0]; cr1=p[1]; cr2=p[2]; cr3=p[3];
      }
      if (st==9 && s<491) {
        uint* dst = &s_chunk[((s>>4)+1)&1][q*256 + c];
        dst[0*16]=cr0.x;  dst[1*16]=cr0.y;  dst[2*16]=cr0.z;  dst[3*16]=cr0.w;
        dst[4*16]=cr1.x;  dst[5*16]=cr1.y;  dst[6*16]=cr1.z;  dst[7*16]=cr1.w;
        dst[8*16]=cr2.x;  dst[9*16]=cr2.y;  dst[10*16]=cr2.z; dst[11*16]=cr2.w;
        dst[12*16]=cr3.x; dst[13*16]=cr3.y; dst[14*16]=cr3.z; dst[15*16]=cr3.w;
      }
    }
    wg_sync();   // ONE barrier per step (lgkm-only)
  }
}

// ---------------------------------------------------------------------------
// MFMA heads (unchanged from the verified round-5 kernel). 512 WGs x 256 thr.
// Waves {0,1} = t-head, {2,3} = y-head; wave wv&1 owns 4 of 8 unit-tiles.
// Next tile's h/a/t loads issued BEFORE the per-tile lgkm-only barrier.
// Layer-2 deduped: wave uh handles tiles with ti&1==uh.
// ---------------------------------------------------------------------------
template<bool H16>
__global__ __launch_bounds__(256,2) void k_heads(
  const float* __restrict__ tW1, const float* __restrict__ tb1,
  const float* __restrict__ tW2, const float* __restrict__ tb2,
  const float* __restrict__ yW1, const float* __restrict__ yW2, const float* __restrict__ yb2,
  const int* __restrict__ a, const int* __restrict__ tt,
  const float* __restrict__ w_yx,
  const float* __restrict__ a_emb, const float* __restrict__ t_emb,
  const float* __restrict__ h_f32, const uint* __restrict__ h16,
  float* __restrict__ o_y, float* __restrict__ o_t, float* __restrict__ o_h)
{
  const int tid = threadIdx.x;
  const int wv = tid>>6, lane = tid&63, q = lane>>4, c = lane&15;
  const bool isY = (wv >= 2);
  const int uh = wv&1;          // unit half (0: units 0-63, 1: 64-127)
  const int pair = wv>>1;       // 0 = t-head pair, 1 = y-head pair
  const int p0 = blockIdx.x*1024;
  const int b0 = blockIdx.x*2;

  __shared__ __align__(16) uint s_al[100*20];      // a_emb packed f16, stride 20
  __shared__ __align__(16) uint s_te[32];          // t_emb packed f16 [4][8]
  __shared__ __align__(16) uint s_gb[2][2][16*68]; // [pair][parity][c*68 + word]

  for (int d = tid; d < 1600; d += 256) {
    int row = d>>4, col = d&15;
    s_al[row*20+col] = packh2(a_emb[row*32+2*col], a_emb[row*32+2*col+1]);
  }
  if (tid < 32) {
    int row = tid>>3, col = tid&7;
    s_te[row*8+col] = packh2(t_emb[row*16+2*col], t_emb[row*16+2*col+1]);
  }

  // ---- stationary first-layer weights: wf[ut*6+kt], unit = uh*64 + ut*16 + c
  half8 wf[24];
  const float* W1 = isY ? yW1 : tW1;
  const int w1stride = isY ? 304 : 128;
  #pragma unroll
  for (int ut=0;ut<4;++ut) {
    const int unit = uh*64 + ut*16 + c;
    #pragma unroll
    for (int kt=0;kt<4;++kt) wf[ut*6+kt] = cvt8(W1 + unit*w1stride + kt*32 + q*8);
    #pragma unroll
    for (int kt=4;kt<6;++kt) {
      half8 hv;
      #pragma unroll
      for (int j=0;j<8;++j) {
        int k2 = (kt-4)*32 + q*8 + j;
        float v = (isY && k2 < 48) ? yW1[unit*304 + 256 + k2] : 0.f;
        hv[j] = (_Float16)v;
      }
      wf[ut*6+kt] = hv;
    }
  }
  // ---- second-layer A-frags
  half8 w2f[4];
  #pragma unroll
  for (int kt=0;kt<4;++kt) {
    half8 hv;
    #pragma unroll
    for (int j=0;j<8;++j) {
      float v = 0.f;
      if (!isY && c < 4) v = tW2[c*128 + kt*32 + q*8 + j];
      if ( isY && c == 0) v = yW2[kt*32 + q*8 + j];
      hv[j] = (_Float16)v;
    }
    w2f[kt] = hv;
  }
  float tb2r[4]; float yb2s = yb2[0];
  #pragma unroll
  for (int r=0;r<4;++r) tb2r[r] = tb2[r];
  // first-layer pre-adds for both samples of this WG
  f32x4 bsr0[4], bsr1[4];
  #pragma unroll
  for (int ut=0;ut<4;++ut)
    #pragma unroll
    for (int r=0;r<4;++r) {
      const int u = uh*64 + ut*16 + q*4 + r;
      bsr0[ut][r] = isY ? w_yx[(b0+0)*128 + u] : tb1[u];
      bsr1[ut][r] = isY ? w_yx[(b0+1)*128 + u] : tb1[u];
    }

  __syncthreads();

  // ---- preload tile 0
  half8 hbn[4];
  int avn = 0, tvn = 0;
  if (H16) {
    const uint* hp = h16 + (size_t)(p0 + c)*64;
    #pragma unroll
    for (int kt=0;kt<4;++kt) hbn[kt] = ld_h8(hp + kt*16 + q*4);
  }
  if (isY) { avn = a[p0 + c]; tvn = tt[p0 + c]; }

  #pragma unroll 1
  for (int ti=0; ti<64; ++ti) {
    const int par = ti&1;
    const int p = p0 + ti*16 + c;

    // ---- current tile B-frags
    half8 hb[4];
    if (H16) {
      #pragma unroll
      for (int kt=0;kt<4;++kt) hb[kt] = hbn[kt];
    } else {
      const float* hp = h_f32 + (size_t)p*128;
      #pragma unroll
      for (int kt=0;kt<4;++kt) hb[kt] = cvt8(hp + kt*32 + q*8);
    }
    const int av = avn, tv = tvn;

    // H16: t-pair expands h -> f32 o_h (store-and-forget; wave uh stores kt 2uh,2uh+1)
    if (H16 && !isY) {
      float* op = o_h + (size_t)p*128;
      #pragma unroll
      for (int kk=0;kk<2;++kk) {
        const int kt = uh*2 + kk;
        float4 f0 = make_float4((float)hb[kt][0], (float)hb[kt][1], (float)hb[kt][2], (float)hb[kt][3]);
        float4 f1 = make_float4((float)hb[kt][4], (float)hb[kt][5], (float)hb[kt][6], (float)hb[kt][7]);
        *(float4*)(op + kt*32 + q*8)     = f0;
        *(float4*)(op + kt*32 + q*8 + 4) = f1;
      }
    }

    // ---- layer 1 (4 unit-tiles per wave)
    f32x4 acc[4];
    #pragma unroll
    for (int ut=0;ut<4;++ut) acc[ut] = (ti < 32) ? bsr0[ut] : bsr1[ut];
    #pragma unroll
    for (int kt=0;kt<4;++kt)
      #pragma unroll
      for (int ut=0;ut<4;++ut) acc[ut] = MFMA(wf[ut*6+kt], hb[kt], acc[ut]);
    if (isY) {
      half8 eb[2];
      eb[0] = ld_h8(&s_al[av*20 + q*4]);
      if (q < 2) eb[1] = ld_h8(&s_te[tv*8 + q*4]);
      else {
        half8 z;
        #pragma unroll
        for (int j=0;j<8;++j) z[j] = (_Float16)0.f;
        eb[1] = z;
      }
      #pragma unroll
      for (int kt=4;kt<6;++kt)
        #pragma unroll
        for (int ut=0;ut<4;++ut) acc[ut] = MFMA(wf[ut*6+kt], eb[kt-4], acc[ut]);
    }

    // ---- gelu, pack into pair-shared double-buffered LDS
    #pragma unroll
    for (int ut=0;ut<4;++ut)
      #pragma unroll
      for (int pr=0;pr<2;++pr) {
        float g0 = gelu_exact(acc[ut][2*pr]);
        float g1 = gelu_exact(acc[ut][2*pr+1]);
        s_gb[pair][par][c*68 + uh*32 + ut*8 + 2*q + pr] = packh2(g0, g1);
      }

    // ---- prefetch next tile (issues before the barrier; no vmcnt drain)
    {
      const int tn = (ti < 63) ? ti+1 : 63;
      const int pn = p0 + tn*16 + c;
      if (H16) {
        const uint* hp = h16 + (size_t)pn*64;
        #pragma unroll
        for (int kt=0;kt<4;++kt) hbn[kt] = ld_h8(hp + kt*16 + q*4);
      }
      if (isY) { avn = a[pn]; tvn = tt[pn]; }
    }

    wg_sync();   // pair halves visible (lgkm-only)

    // ---- layer 2 (deduped: wave uh handles its parity)
    if (par == uh) {
      f32x4 a2; a2[0]=0.f; a2[1]=0.f; a2[2]=0.f; a2[3]=0.f;
      #pragma unroll
      for (int kt=0;kt<4;++kt) {
        half8 gb = ld_h8(&s_gb[pair][par][c*68 + kt*16 + q*4]);
        a2 = MFMA(w2f[kt], gb, a2);
      }
      if (lane < 16) {
        if (!isY) {
          float4 o = make_float4(a2[0]+tb2r[0], a2[1]+tb2r[1], a2[2]+tb2r[2], a2[3]+tb2r[3]);
          *(float4*)&o_t[(size_t)p*4] = o;
        } else {
          o_y[p] = a2[0] + yb2s;
        }
      }
    }
  }
}

// ---------------------------------------------------------------------------
extern "C" void kernel_launch(void* const* d_in, const int* in_sizes, int n_in,
                              void* d_out, int out_size, void* d_ws, size_t ws_size,
                              hipStream_t stream) {
  (void)in_sizes; (void)n_in; (void)out_size;
  const float* x     = (const float*)d_in[0];
  const int*   a     = (const int*)  d_in[1];
  const int*   tt    = (const int*)  d_in[2];
  const float* y     = (const float*)d_in[3];
  const float* mask  = (const float*)d_in[4];
  const float* xW    = (const float*)d_in[5];
  const float* xb    = (const float*)d_in[6];
  const float* a_emb = (const float*)d_in[7];
  const float* t_emb = (const float*)d_in[8];
  const float* W_ih  = (const float*)d_in[9];
  const float* b_ih  = (const float*)d_in[10];
  const float* W_hh  = (const float*)d_in[11];
  const float* b_hh  = (const float*)d_in[12];
  const float* h0W   = (const float*)d_in[13];
  const float* h0b   = (const float*)d_in[14];
  const float* tW1   = (const float*)d_in[15];
  const float* tb1   = (const float*)d_in[16];
  const float* tW2   = (const float*)d_in[17];
  const float* tb2   = (const float*)d_in[18];
  const float* yW1   = (const float*)d_in[19];
  const float* yb1   = (const float*)d_in[20];
  const float* yW2   = (const float*)d_in[21];
  const float* yb2   = (const float*)d_in[22];

  float* o_y = (float*)d_out;                  // [B,S,1]   524288
  float* o_t = o_y + 524288;                   // [B,S,4]   2097152
  float* o_h = o_y + 2621440;                  // [B,S,128] 67108864

  float* ws    = (float*)d_ws;
  float* w_h0  = ws;                 // 131072
  float* w_xgx = ws + 131072;        // 393216
  float* w_yx  = ws + 524288;        // 131072

  // f16 h hand-off buffer if the workspace allows (134 MB)
  const size_t H16_BYTES = (size_t)524288 * 256;
  uint* h16 = nullptr;
  if (ws_size >= (size_t)655360*4 + H16_BYTES) h16 = (uint*)(ws + 655360);

  k_sample<<<1024, 384, 0, stream>>>(x, xW, xb, h0W, h0b, W_ih, b_ih, b_hh, yW1, yb1,
                                     w_h0, w_xgx, w_yx);
  k_recur<<<64, 512, 0, stream>>>(W_hh, W_ih, b_hh, a, tt, y, mask,
                                  w_h0, w_xgx, a_emb, t_emb, o_h, h16);
  if (h16)
    k_heads<true><<<512, 256, 0, stream>>>(tW1, tb1, tW2, tb2, yW1, yW2, yb2, a, tt,
                                           w_yx, a_emb, t_emb, o_h, h16, o_y, o_t, o_h);
  else
    k_heads<false><<<512, 256, 0, stream>>>(tW1, tb1, tW2, tb2, yW1, yW2, yb2, a, tt,
                                            w_yx, a_emb, t_emb, o_h, nullptr, o_y, o_t, o_h);
}

// Round 9
// 1092.774 us; speedup vs baseline: 1.8260x; 1.0145x over previous
//
#include <hip/hip_runtime.h>
#include <math.h>

#define SLEN 512

typedef _Float16 half8 __attribute__((ext_vector_type(8)));
typedef _Float16 half2v __attribute__((ext_vector_type(2)));
typedef __fp16 fp16x2 __attribute__((ext_vector_type(2)));
typedef float f32x4 __attribute__((ext_vector_type(4)));
typedef unsigned int uint;

union U4H8 { uint4 u; half8 h; };
union UH2 { uint u; half2v v; fp16x2 p; };

static __device__ __forceinline__ uint packh2(float a, float b){
  UH2 x; x.p = __builtin_amdgcn_cvt_pkrtz(a, b); return x.u;
}
static __device__ __forceinline__ half8 ld_h8(const uint* p){
  U4H8 x; x.u = *(const uint4*)p; return x.h;
}
static __device__ __forceinline__ float rcpf(float x){ return __builtin_amdgcn_rcpf(x); }
static __device__ __forceinline__ float sigm(float v){ return rcpf(1.0f+__expf(-v)); }
static __device__ __forceinline__ float tanh_f(float v){ return 1.0f - 2.0f*rcpf(__expf(2.0f*v)+1.0f); }
// Abramowitz-Stegun 7.1.26 erf: |err| <= 1.5e-7, ~20 VALU ops, branch-free.
// Replaces the ROCm erff libcall (multi-hundred-instruction IEEE routine)
// that dominated k_heads' runtime.
static __device__ __forceinline__ float erf_fast(float x){
  float ax = fabsf(x);
  float t = rcpf(fmaf(0.3275911f, ax, 1.0f));
  float p = fmaf(1.061405429f, t, -1.453152027f);
  p = fmaf(p, t, 1.421413741f);
  p = fmaf(p, t, -0.284496736f);
  p = fmaf(p, t, 0.254829592f);
  p = p * t;
  float e = __expf(-ax*ax);
  float r = fmaf(-p, e, 1.0f);
  return copysignf(r, x);
}
static __device__ __forceinline__ float gelu_exact(float v){
  return 0.5f*v*(1.0f+erf_fast(v*0.7071067811865475f));
}
static __device__ __forceinline__ half8 cvt8(const float* p){
  const float4* fp = (const float4*)p;
  float4 v0 = fp[0], v1 = fp[1];
  half8 hv;
  hv[0]=(_Float16)v0.x; hv[1]=(_Float16)v0.y; hv[2]=(_Float16)v0.z; hv[3]=(_Float16)v0.w;
  hv[4]=(_Float16)v1.x; hv[5]=(_Float16)v1.y; hv[6]=(_Float16)v1.z; hv[7]=(_Float16)v1.w;
  return hv;
}
#define MFMA(a,b,c) __builtin_amdgcn_mfma_f32_16x16x32_f16((a),(b),(c),0,0,0)

// LDS-visibility-only workgroup barrier (no vmcnt drain).
static __device__ __forceinline__ void wg_sync(){
  asm volatile("s_waitcnt lgkmcnt(0)" ::: "memory");
  __builtin_amdgcn_s_barrier();
}

// ---------------------------------------------------------------------------
// Per-sample precompute: x_enc -> h0[b,128], x_gx[b,384] (+b_ih, +b_hh r/z), yx[b,128] (+yb1)
// xW/h0W/yW1 rows are 16B-aligned -> float4 loads; W_ih rows (708B) stay scalar.
// ---------------------------------------------------------------------------
__global__ void k_sample(const float* __restrict__ x, const float* __restrict__ xW, const float* __restrict__ xb,
                         const float* __restrict__ h0W, const float* __restrict__ h0b,
                         const float* __restrict__ W_ih, const float* __restrict__ b_ih, const float* __restrict__ b_hh,
                         const float* __restrict__ yW1, const float* __restrict__ yb1,
                         float* __restrict__ w_h0, float* __restrict__ w_xgx, float* __restrict__ w_yx)
{
  const int b = blockIdx.x, tid = threadIdx.x;   // 384 threads
  __shared__ float sx[128];
  __shared__ float sxe[128];
  if (tid < 128) sx[tid] = x[b*128+tid];
  __syncthreads();
  if (tid < 128) {
    float acc = xb[tid];
    const float4* wr = (const float4*)(xW + tid*128);
    #pragma unroll 8
    for (int j=0;j<32;++j) {
      float4 w = wr[j];
      acc += w.x*sx[4*j] + w.y*sx[4*j+1] + w.z*sx[4*j+2] + w.w*sx[4*j+3];
    }
    sxe[tid] = acc;
  }
  __syncthreads();
  {
    const int o = tid;
    float acc = b_ih[o] + (o < 256 ? b_hh[o] : 0.f);   // fold b_hh for r,z only
    #pragma unroll 8
    for (int j=0;j<128;++j) acc += W_ih[o*177+j]*sxe[j];
    w_xgx[b*384+o] = acc;
  }
  if (tid < 128) {
    float acc = h0b[tid];
    const float4* hr = (const float4*)(h0W + tid*128);
    #pragma unroll 8
    for (int j=0;j<32;++j) {
      float4 w = hr[j];
      acc += w.x*sxe[4*j] + w.y*sxe[4*j+1] + w.z*sxe[4*j+2] + w.w*sxe[4*j+3];
    }
    w_h0[b*128+tid] = tanhf(acc);
    float a2 = yb1[tid];
    const float4* yr = (const float4*)(yW1 + tid*304 + 128);
    #pragma unroll 8
    for (int j=0;j<32;++j) {
      float4 w = yr[j];
      a2 += w.x*sxe[4*j] + w.y*sxe[4*j+1] + w.z*sxe[4*j+2] + w.w*sxe[4*j+3];
    }
    w_yx[b*128+tid] = a2;
  }
}

// ---------------------------------------------------------------------------
// MFMA recurrence, ONE lgkm-only barrier per step. 64 WGs x 512 thr (8 waves),
// 16 samples per WG. Wave wv owns h-rows [wv*16, wv*16+16) of r,z,n; GRU
// combine is register-local; h(s) stored straight from registers to h16 (f16)
// or o_h (f32 fallback). LDS anti-conflict: s_h slots XOR-swizzled by (c&7);
// s_chunk transposed to [arr][st][sample]; s_al stride 20.
// ---------------------------------------------------------------------------
__global__ __launch_bounds__(512,1) void k_recur(
  const float* __restrict__ W_hh, const float* __restrict__ W_ih, const float* __restrict__ b_hh,
  const int* __restrict__ a, const int* __restrict__ tt,
  const float* __restrict__ yy, const float* __restrict__ mask,
  const float* __restrict__ w_h0, const float* __restrict__ w_xgx,
  const float* __restrict__ a_emb, const float* __restrict__ t_emb,
  float* __restrict__ o_h, uint* __restrict__ h16)
{
  const int tid = threadIdx.x;
  const int wv = tid>>6, lane = tid&63, q = lane>>4, c = lane&15;
  const int b0 = blockIdx.x*16;
  const int r0 = wv*16;
  const int swz = c&7;

  __shared__ __align__(16) uint s_h[2][16*64];     // h f16, slot-swizzled
  __shared__ __align__(16) uint s_chunk[2][1024];  // [par][arr*256 + st*16 + c]
  __shared__ __align__(16) uint s_al[100*20];      // a_emb packed f16, stride 20
  __shared__ __align__(16) uint s_te[32];          // t_emb packed f16 [4][8]

  // ---- stationary weight A-frags: wf[g*6+kt], g=0(r),1(z),2(n)
  half8 wf[18];
  #pragma unroll
  for (int g=0; g<3; ++g) {
    const int row = g*128 + r0 + c;
    #pragma unroll
    for (int kt=0; kt<4; ++kt) wf[g*6+kt] = cvt8(W_hh + row*128 + kt*32 + q*8);
    #pragma unroll
    for (int kt=4; kt<6; ++kt) {
      half8 hv;
      #pragma unroll
      for (int j=0;j<8;++j) {
        int k2 = (kt-4)*32 + q*8 + j;
        float v = (k2 < 49) ? W_ih[row*177 + 128 + k2] : 0.f;
        hv[j] = (_Float16)v;
      }
      wf[g*6+kt] = hv;
    }
  }
  // per-lane state: 4 rows (r0 + q*4 + j) x sample c
  f32x4 xgr, xgz, xgn, bhh, hm;
  #pragma unroll
  for (int j=0;j<4;++j) {
    const int rr = r0 + q*4 + j;
    xgr[j] = w_xgx[(b0+c)*384 +       rr];
    xgz[j] = w_xgx[(b0+c)*384 + 128 + rr];
    xgn[j] = w_xgx[(b0+c)*384 + 256 + rr];
    bhh[j] = b_hh[256 + rr];
    hm[j]  = w_h0[(b0+c)*128 + rr];
  }
  // stage embedding tables (packed f16, stride 20)
  for (int d = tid; d < 1600; d += 512) {
    int row = d>>4, col = d&15;
    s_al[row*20+col] = packh2(a_emb[row*32+2*col], a_emb[row*32+2*col+1]);
  }
  if (tid < 32) {
    int row = tid>>3, col = tid&7;
    s_te[tid] = packh2(t_emb[row*16+2*col], t_emb[row*16+2*col+1]);
  }
  // chunk 0 (wave 0), transposed [arr][st][c]
  uint4 cr0, cr1, cr2, cr3;
  if (wv==0) {
    const uint* bp = (q==0) ? (const uint*)a : (q==1) ? (const uint*)tt
                   : (q==2) ? (const uint*)yy : (const uint*)mask;
    const uint4* p = (const uint4*)(bp + (size_t)(b0+c)*512);
    cr0=p[0]; cr1=p[1]; cr2=p[2]; cr3=p[3];
    uint* dst = &s_chunk[0][q*256 + c];
    dst[0*16]=cr0.x;  dst[1*16]=cr0.y;  dst[2*16]=cr0.z;  dst[3*16]=cr0.w;
    dst[4*16]=cr1.x;  dst[5*16]=cr1.y;  dst[6*16]=cr1.z;  dst[7*16]=cr1.w;
    dst[8*16]=cr2.x;  dst[9*16]=cr2.y;  dst[10*16]=cr2.z; dst[11*16]=cr2.w;
    dst[12*16]=cr3.x; dst[13*16]=cr3.y; dst[14*16]=cr3.z; dst[15*16]=cr3.w;
  }
  // h0 -> s_h[0] (swizzled slots)
  {
    const int slot = wv*2 + (q>>1);
    const int hidx = c*64 + ((slot ^ swz)<<2) + (q&1)*2;
    uint2 u; u.x = packh2(hm[0], hm[1]); u.y = packh2(hm[2], hm[3]);
    *(uint2*)&s_h[0][hidx] = u;
  }
  __syncthreads();

  for (int s=0; s<SLEN; ++s) {
    const int pb = s&1, par = (s>>4)&1, st = s&15;
    // ---- h B-frags (swizzled)
    half8 hb[4];
    #pragma unroll
    for (int kt=0;kt<4;++kt) hb[kt] = ld_h8(&s_h[pb][c*64 + (((kt*4+q)^swz)<<2)]);
    // ---- chunk scalars (transposed: conflict-free, q-broadcast)
    const int av = (int)s_chunk[par][        st*16 + c];
    const int tv = (int)s_chunk[par][256   + st*16 + c];
    const float yv   = __uint_as_float(s_chunk[par][512 + st*16 + c]);
    const float mval = __uint_as_float(s_chunk[par][768 + st*16 + c]);
    half8 eb0 = ld_h8(&s_al[av*20 + q*4]);
    half8 eb1;
    if (q < 2) eb1 = ld_h8(&s_te[tv*8 + q*4]);
    else { U4H8 t; t.u = make_uint4((q==2)?packh2(yv,0.f):0u,0u,0u,0u); eb1 = t.h; }
    // ---- store h(s) (pre-update state) straight from registers
    {
      const size_t p = (size_t)(b0+c)*SLEN + s;
      if (h16) {
        uint2 u; u.x = packh2(hm[0], hm[1]); u.y = packh2(hm[2], hm[3]);
        *(uint2*)(h16 + p*64 + wv*8 + q*2) = u;
      } else {
        *(float4*)(o_h + p*128 + r0 + q*4) = make_float4(hm[0],hm[1],hm[2],hm[3]);
      }
    }
    // ---- 18 MFMA: r(6), z(6), n_h(4), n_x(2)
    f32x4 ar = xgr, az = xgz, anh = bhh, anx = xgn;
    #pragma unroll
    for (int kt=0;kt<4;++kt) {
      ar  = MFMA(wf[kt],      hb[kt], ar);
      az  = MFMA(wf[6+kt],    hb[kt], az);
      anh = MFMA(wf[12+kt],   hb[kt], anh);
    }
    ar  = MFMA(wf[4],  eb0, ar);   ar  = MFMA(wf[5],  eb1, ar);
    az  = MFMA(wf[10], eb0, az);   az  = MFMA(wf[11], eb1, az);
    anx = MFMA(wf[16], eb0, anx);  anx = MFMA(wf[17], eb1, anx);
    // ---- register-local GRU combine
    #pragma unroll
    for (int j=0;j<4;++j) {
      float rj = sigm(ar[j]), zj = sigm(az[j]);
      float nj = tanh_f(anx[j] + rj*anh[j]);
      float hn = nj + zj*(hm[j] - nj);
      hm[j] = hm[j] + mval*(hn - hm[j]);
    }
    // ---- write h(s+1) (swizzled)
    {
      const int slot = wv*2 + (q>>1);
      const int hidx = c*64 + ((slot ^ swz)<<2) + (q&1)*2;
      uint2 u; u.x = packh2(hm[0], hm[1]); u.y = packh2(hm[2], hm[3]);
      *(uint2*)&s_h[(s+1)&1][hidx] = u;
    }
    // ---- chunk prefetch (wave 0), transposed store
    if (wv==0) {
      if (st==8 && s<490) {
        const int s0n = ((s>>4)+1)*16;
        const uint* bp = (q==0) ? (const uint*)a : (q==1) ? (const uint*)tt
                       : (q==2) ? (const uint*)yy : (const uint*)mask;
        const uint4* p = (const uint4*)(bp + (size_t)(b0+c)*512 + s0n);
        cr0=p[0]; cr1=p[1]; cr2=p[2]; cr3=p[3];
      }
      if (st==9 && s<491) {
        uint* dst = &s_chunk[((s>>4)+1)&1][q*256 + c];
        dst[0*16]=cr0.x;  dst[1*16]=cr0.y;  dst[2*16]=cr0.z;  dst[3*16]=cr0.w;
        dst[4*16]=cr1.x;  dst[5*16]=cr1.y;  dst[6*16]=cr1.z;  dst[7*16]=cr1.w;
        dst[8*16]=cr2.x;  dst[9*16]=cr2.y;  dst[10*16]=cr2.z; dst[11*16]=cr2.w;
        dst[12*16]=cr3.x; dst[13*16]=cr3.y; dst[14*16]=cr3.z; dst[15*16]=cr3.w;
      }
    }
    wg_sync();   // ONE barrier per step (lgkm-only)
  }
}

// ---------------------------------------------------------------------------
// MFMA heads (structure unchanged from the verified round-8 kernel; only
// gelu's erf is now the inline A&S approximation). 512 WGs x 256 thr.
// ---------------------------------------------------------------------------
template<bool H16>
__global__ __launch_bounds__(256,2) void k_heads(
  const float* __restrict__ tW1, const float* __restrict__ tb1,
  const float* __restrict__ tW2, const float* __restrict__ tb2,
  const float* __restrict__ yW1, const float* __restrict__ yW2, const float* __restrict__ yb2,
  const int* __restrict__ a, const int* __restrict__ tt,
  const float* __restrict__ w_yx,
  const float* __restrict__ a_emb, const float* __restrict__ t_emb,
  const float* __restrict__ h_f32, const uint* __restrict__ h16,
  float* __restrict__ o_y, float* __restrict__ o_t, float* __restrict__ o_h)
{
  const int tid = threadIdx.x;
  const int wv = tid>>6, lane = tid&63, q = lane>>4, c = lane&15;
  const bool isY = (wv >= 2);
  const int uh = wv&1;          // unit half (0: units 0-63, 1: 64-127)
  const int pair = wv>>1;       // 0 = t-head pair, 1 = y-head pair
  const int p0 = blockIdx.x*1024;
  const int b0 = blockIdx.x*2;

  __shared__ __align__(16) uint s_al[100*20];      // a_emb packed f16, stride 20
  __shared__ __align__(16) uint s_te[32];          // t_emb packed f16 [4][8]
  __shared__ __align__(16) uint s_gb[2][2][16*68]; // [pair][parity][c*68 + word]

  for (int d = tid; d < 1600; d += 256) {
    int row = d>>4, col = d&15;
    s_al[row*20+col] = packh2(a_emb[row*32+2*col], a_emb[row*32+2*col+1]);
  }
  if (tid < 32) {
    int row = tid>>3, col = tid&7;
    s_te[row*8+col] = packh2(t_emb[row*16+2*col], t_emb[row*16+2*col+1]);
  }

  // ---- stationary first-layer weights: wf[ut*6+kt], unit = uh*64 + ut*16 + c
  half8 wf[24];
  const float* W1 = isY ? yW1 : tW1;
  const int w1stride = isY ? 304 : 128;
  #pragma unroll
  for (int ut=0;ut<4;++ut) {
    const int unit = uh*64 + ut*16 + c;
    #pragma unroll
    for (int kt=0;kt<4;++kt) wf[ut*6+kt] = cvt8(W1 + unit*w1stride + kt*32 + q*8);
    #pragma unroll
    for (int kt=4;kt<6;++kt) {
      half8 hv;
      #pragma unroll
      for (int j=0;j<8;++j) {
        int k2 = (kt-4)*32 + q*8 + j;
        float v = (isY && k2 < 48) ? yW1[unit*304 + 256 + k2] : 0.f;
        hv[j] = (_Float16)v;
      }
      wf[ut*6+kt] = hv;
    }
  }
  // ---- second-layer A-frags
  half8 w2f[4];
  #pragma unroll
  for (int kt=0;kt<4;++kt) {
    half8 hv;
    #pragma unroll
    for (int j=0;j<8;++j) {
      float v = 0.f;
      if (!isY && c < 4) v = tW2[c*128 + kt*32 + q*8 + j];
      if ( isY && c == 0) v = yW2[kt*32 + q*8 + j];
      hv[j] = (_Float16)v;
    }
    w2f[kt] = hv;
  }
  float tb2r[4]; float yb2s = yb2[0];
  #pragma unroll
  for (int r=0;r<4;++r) tb2r[r] = tb2[r];
  // first-layer pre-adds for both samples of this WG
  f32x4 bsr0[4], bsr1[4];
  #pragma unroll
  for (int ut=0;ut<4;++ut)
    #pragma unroll
    for (int r=0;r<4;++r) {
      const int u = uh*64 + ut*16 + q*4 + r;
      bsr0[ut][r] = isY ? w_yx[(b0+0)*128 + u] : tb1[u];
      bsr1[ut][r] = isY ? w_yx[(b0+1)*128 + u] : tb1[u];
    }

  __syncthreads();

  // ---- preload tile 0
  half8 hbn[4];
  int avn = 0, tvn = 0;
  if (H16) {
    const uint* hp = h16 + (size_t)(p0 + c)*64;
    #pragma unroll
    for (int kt=0;kt<4;++kt) hbn[kt] = ld_h8(hp + kt*16 + q*4);
  }
  if (isY) { avn = a[p0 + c]; tvn = tt[p0 + c]; }

  #pragma unroll 1
  for (int ti=0; ti<64; ++ti) {
    const int par = ti&1;
    const int p = p0 + ti*16 + c;

    // ---- current tile B-frags
    half8 hb[4];
    if (H16) {
      #pragma unroll
      for (int kt=0;kt<4;++kt) hb[kt] = hbn[kt];
    } else {
      const float* hp = h_f32 + (size_t)p*128;
      #pragma unroll
      for (int kt=0;kt<4;++kt) hb[kt] = cvt8(hp + kt*32 + q*8);
    }
    const int av = avn, tv = tvn;

    // H16: t-pair expands h -> f32 o_h (store-and-forget; wave uh stores kt 2uh,2uh+1)
    if (H16 && !isY) {
      float* op = o_h + (size_t)p*128;
      #pragma unroll
      for (int kk=0;kk<2;++kk) {
        const int kt = uh*2 + kk;
        float4 f0 = make_float4((float)hb[kt][0], (float)hb[kt][1], (float)hb[kt][2], (float)hb[kt][3]);
        float4 f1 = make_float4((float)hb[kt][4], (float)hb[kt][5], (float)hb[kt][6], (float)hb[kt][7]);
        *(float4*)(op + kt*32 + q*8)     = f0;
        *(float4*)(op + kt*32 + q*8 + 4) = f1;
      }
    }

    // ---- layer 1 (4 unit-tiles per wave)
    f32x4 acc[4];
    #pragma unroll
    for (int ut=0;ut<4;++ut) acc[ut] = (ti < 32) ? bsr0[ut] : bsr1[ut];
    #pragma unroll
    for (int kt=0;kt<4;++kt)
      #pragma unroll
      for (int ut=0;ut<4;++ut) acc[ut] = MFMA(wf[ut*6+kt], hb[kt], acc[ut]);
    if (isY) {
      half8 eb[2];
      eb[0] = ld_h8(&s_al[av*20 + q*4]);
      if (q < 2) eb[1] = ld_h8(&s_te[tv*8 + q*4]);
      else {
        half8 z;
        #pragma unroll
        for (int j=0;j<8;++j) z[j] = (_Float16)0.f;
        eb[1] = z;
      }
      #pragma unroll
      for (int kt=4;kt<6;++kt)
        #pragma unroll
        for (int ut=0;ut<4;++ut) acc[ut] = MFMA(wf[ut*6+kt], eb[kt-4], acc[ut]);
    }

    // ---- gelu, pack into pair-shared double-buffered LDS
    #pragma unroll
    for (int ut=0;ut<4;++ut)
      #pragma unroll
      for (int pr=0;pr<2;++pr) {
        float g0 = gelu_exact(acc[ut][2*pr]);
        float g1 = gelu_exact(acc[ut][2*pr+1]);
        s_gb[pair][par][c*68 + uh*32 + ut*8 + 2*q + pr] = packh2(g0, g1);
      }

    // ---- prefetch next tile (issues before the barrier; no vmcnt drain)
    {
      const int tn = (ti < 63) ? ti+1 : 63;
      const int pn = p0 + tn*16 + c;
      if (H16) {
        const uint* hp = h16 + (size_t)pn*64;
        #pragma unroll
        for (int kt=0;kt<4;++kt) hbn[kt] = ld_h8(hp + kt*16 + q*4);
      }
      if (isY) { avn = a[pn]; tvn = tt[pn]; }
    }

    wg_sync();   // pair halves visible (lgkm-only)

    // ---- layer 2 (deduped: wave uh handles its parity)
    if (par == uh) {
      f32x4 a2; a2[0]=0.f; a2[1]=0.f; a2[2]=0.f; a2[3]=0.f;
      #pragma unroll
      for (int kt=0;kt<4;++kt) {
        half8 gb = ld_h8(&s_gb[pair][par][c*68 + kt*16 + q*4]);
        a2 = MFMA(w2f[kt], gb, a2);
      }
      if (lane < 16) {
        if (!isY) {
          float4 o = make_float4(a2[0]+tb2r[0], a2[1]+tb2r[1], a2[2]+tb2r[2], a2[3]+tb2r[3]);
          *(float4*)&o_t[(size_t)p*4] = o;
        } else {
          o_y[p] = a2[0] + yb2s;
        }
      }
    }
  }
}

// ---------------------------------------------------------------------------
extern "C" void kernel_launch(void* const* d_in, const int* in_sizes, int n_in,
                              void* d_out, int out_size, void* d_ws, size_t ws_size,
                              hipStream_t stream) {
  (void)in_sizes; (void)n_in; (void)out_size;
  const float* x     = (const float*)d_in[0];
  const int*   a     = (const int*)  d_in[1];
  const int*   tt    = (const int*)  d_in[2];
  const float* y     = (const float*)d_in[3];
  const float* mask  = (const float*)d_in[4];
  const float* xW    = (const float*)d_in[5];
  const float* xb    = (const float*)d_in[6];
  const float* a_emb = (const float*)d_in[7];
  const float* t_emb = (const float*)d_in[8];
  const float* W_ih  = (const float*)d_in[9];
  const float* b_ih  = (const float*)d_in[10];
  const float* W_hh  = (const float*)d_in[11];
  const float* b_hh  = (const float*)d_in[12];
  const float* h0W   = (const float*)d_in[13];
  const float* h0b   = (const float*)d_in[14];
  const float* tW1   = (const float*)d_in[15];
  const float* tb1   = (const float*)d_in[16];
  const float* tW2   = (const float*)d_in[17];
  const float* tb2   = (const float*)d_in[18];
  const float* yW1   = (const float*)d_in[19];
  const float* yb1   = (const float*)d_in[20];
  const float* yW2   = (const float*)d_in[21];
  const float* yb2   = (const float*)d_in[22];

  float* o_y = (float*)d_out;                  // [B,S,1]   524288
  float* o_t = o_y + 524288;                   // [B,S,4]   2097152
  float* o_h = o_y + 2621440;                  // [B,S,128] 67108864

  float* ws    = (float*)d_ws;
  float* w_h0  = ws;                 // 131072
  float* w_xgx = ws + 131072;        // 393216
  float* w_yx  = ws + 524288;        // 131072

  // f16 h hand-off buffer if the workspace allows (134 MB)
  const size_t H16_BYTES = (size_t)524288 * 256;
  uint* h16 = nullptr;
  if (ws_size >= (size_t)655360*4 + H16_BYTES) h16 = (uint*)(ws + 655360);

  k_sample<<<1024, 384, 0, stream>>>(x, xW, xb, h0W, h0b, W_ih, b_ih, b_hh, yW1, yb1,
                                     w_h0, w_xgx, w_yx);
  k_recur<<<64, 512, 0, stream>>>(W_hh, W_ih, b_hh, a, tt, y, mask,
                                  w_h0, w_xgx, a_emb, t_emb, o_h, h16);
  if (h16)
    k_heads<true><<<512, 256, 0, stream>>>(tW1, tb1, tW2, tb2, yW1, yW2, yb2, a, tt,
                                           w_yx, a_emb, t_emb, o_h, h16, o_y, o_t, o_h);
  else
    k_heads<false><<<512, 256, 0, stream>>>(tW1, tb1, tW2, tb2, yW1, yW2, yb2, a, tt,
                                            w_yx, a_emb, t_emb, o_h, nullptr, o_y, o_t, o_h);
}